// Round 1
// baseline (403.638 us; speedup 1.0000x reference)
//
#include <hip/hip_runtime.h>
#include <math.h>

#define C_DIM 128
#define TQ 32
#define TK 128
#define NPIX 4096
#define NTHREADS 256

// Fused attention-to-grid-expectation kernel.
// out[b,q,:] = (E_attn[gx], E_attn[gy]) / 64 * 2 - 1, attn = softmax(x^T y / sqrt(c))
__global__ __launch_bounds__(NTHREADS, 2) void uv_attn_kernel(
    const float* __restrict__ x, const float* __restrict__ y, float* __restrict__ out)
{
    __shared__ float Xs[C_DIM][TQ];   // 16 KB, pre-scaled by 1/sqrt(c)
    __shared__ float Ys[64][TK];      // 32 KB, one 64-channel chunk at a time

    const int tid  = threadIdx.x;
    const int wgid = blockIdx.x;

    // XCD swizzle: pin batch -> XCD so each XCD's L2 holds one batch's Y panel (2 MB)
    const int xcd   = wgid & 7;
    const int jj_   = wgid >> 3;            // 0..63
    const int b     = xcd & 3;
    const int qtile = ((xcd >> 2) << 6) | jj_;  // 0..127
    const int q0    = qtile * TQ;

    const float scale = 0.08838834764831845f;   // 1/sqrt(128)

    // ---- stage X tile (c-major), pre-scaled ----
    const float* xb = x + (size_t)b * C_DIM * NPIX + q0;
    {
        const int cr = tid >> 3;            // channel row 0..31 (+32*i)
        const int cc = (tid & 7) << 2;      // float4 col within 32-query row
        #pragma unroll
        for (int i = 0; i < 4; ++i) {
            float4 v = *(const float4*)(xb + (size_t)(cr + (i << 5)) * NPIX + cc);
            v.x *= scale; v.y *= scale; v.z *= scale; v.w *= scale;
            *(float4*)(&Xs[cr + (i << 5)][cc]) = v;
        }
    }

    // ---- per-thread tile assignment: 2 query rows x 8 key cols ----
    const int rg     = tid >> 4;        // row group 0..15
    const int lane16 = tid & 15;        // 16 lanes cover 128 key cols
    const int r0     = rg << 1;
    const int col0   = lane16 << 3;

    float gxv[8];
    #pragma unroll
    for (int j2 = 0; j2 < 8; ++j2)
        gxv[j2] = (float)((col0 & 63) + j2) + 0.5f;   // k%64 + 0.5 (tile-invariant)
    const float gyb = (float)(lane16 >> 3) + 0.5f;    // (k/64)%2 part; + 2*kt per tile

    float m_run[2] = {-INFINITY, -INFINITY};
    float den[2]   = {0.f, 0.f};
    float nu[2]    = {0.f, 0.f};
    float nv[2]    = {0.f, 0.f};

    const int yr = tid >> 5;            // 0..7 (+8*i)
    const int yc = (tid & 31) << 2;     // float4 col within 128-key row
    const float* ybase = y + (size_t)b * C_DIM * NPIX;

    for (int kt = 0; kt < NPIX / TK; ++kt) {
        float S[2][8];
        #pragma unroll
        for (int r = 0; r < 2; ++r)
            #pragma unroll
            for (int j2 = 0; j2 < 8; ++j2) S[r][j2] = 0.f;

        #pragma unroll
        for (int cb = 0; cb < 2; ++cb) {
            __syncthreads();   // previous consumers of Ys done (also orders Xs stage on kt=0)
            const float* yt = ybase + (size_t)(cb << 6) * NPIX + kt * TK;
            #pragma unroll
            for (int i = 0; i < 8; ++i) {
                *(float4*)(&Ys[yr + (i << 3)][yc]) =
                    *(const float4*)(yt + (size_t)(yr + (i << 3)) * NPIX + yc);
            }
            __syncthreads();

            const int cbase = cb << 6;
            #pragma unroll 16
            for (int c = 0; c < 64; ++c) {
                const float2 xa  = *(const float2*)(&Xs[cbase + c][r0]);
                const float4 ya  = *(const float4*)(&Ys[c][col0]);
                const float4 yb4 = *(const float4*)(&Ys[c][col0 + 4]);
                S[0][0] += xa.x * ya.x;  S[0][1] += xa.x * ya.y;
                S[0][2] += xa.x * ya.z;  S[0][3] += xa.x * ya.w;
                S[0][4] += xa.x * yb4.x; S[0][5] += xa.x * yb4.y;
                S[0][6] += xa.x * yb4.z; S[0][7] += xa.x * yb4.w;
                S[1][0] += xa.y * ya.x;  S[1][1] += xa.y * ya.y;
                S[1][2] += xa.y * ya.z;  S[1][3] += xa.y * ya.w;
                S[1][4] += xa.y * yb4.x; S[1][5] += xa.y * yb4.y;
                S[1][6] += xa.y * yb4.z; S[1][7] += xa.y * yb4.w;
            }
        }

        // ---- online softmax update (per query row) ----
        const float gy = gyb + 2.0f * (float)kt;
        #pragma unroll
        for (int r = 0; r < 2; ++r) {
            float tmax = S[r][0];
            #pragma unroll
            for (int j2 = 1; j2 < 8; ++j2) tmax = fmaxf(tmax, S[r][j2]);
            #pragma unroll
            for (int mk = 8; mk >= 1; mk >>= 1)
                tmax = fmaxf(tmax, __shfl_xor(tmax, mk, 16));
            const float mnew  = fmaxf(m_run[r], tmax);
            const float alpha = __expf(m_run[r] - mnew);   // exp(-inf)=0 on first tile
            m_run[r] = mnew;
            float psum = 0.f, pu = 0.f;
            #pragma unroll
            for (int j2 = 0; j2 < 8; ++j2) {
                const float p = __expf(S[r][j2] - mnew);
                psum += p;
                pu   += p * gxv[j2];
            }
            den[r] = den[r] * alpha + psum;
            nu[r]  = nu[r]  * alpha + pu;
            nv[r]  = nv[r]  * alpha + gy * psum;   // gy constant across this thread's 8 cols
        }
    }

    // ---- reduce partials across the 16 lanes of each row group ----
    #pragma unroll
    for (int r = 0; r < 2; ++r) {
        #pragma unroll
        for (int mk = 8; mk >= 1; mk >>= 1) {
            den[r] += __shfl_xor(den[r], mk, 16);
            nu[r]  += __shfl_xor(nu[r],  mk, 16);
            nv[r]  += __shfl_xor(nv[r],  mk, 16);
        }
    }
    if (lane16 == 0) {
        #pragma unroll
        for (int r = 0; r < 2; ++r) {
            const float inv = 1.0f / den[r];
            const float u = nu[r] * inv * 0.03125f - 1.0f;  // /64*2 - 1
            const float v = nv[r] * inv * 0.03125f - 1.0f;
            const int q = q0 + r0 + r;
            *(float2*)(out + ((size_t)b * NPIX + q) * 2) = make_float2(u, v);
        }
    }
}

extern "C" void kernel_launch(void* const* d_in, const int* in_sizes, int n_in,
                              void* d_out, int out_size, void* d_ws, size_t ws_size,
                              hipStream_t stream) {
    const float* x = (const float*)d_in[0];
    const float* y = (const float*)d_in[1];
    float* out = (float*)d_out;
    dim3 grid(512), block(NTHREADS);
    hipLaunchKernelGGL(uv_attn_kernel, grid, block, 0, stream, x, y, out);
}

// Round 2
// 132.986 us; speedup vs baseline: 3.0352x; 3.0352x over previous
//
#include <hip/hip_runtime.h>
#include <math.h>

typedef __attribute__((ext_vector_type(8))) short bf16x8;
typedef __attribute__((ext_vector_type(4))) float f32x4;

#define NPIX 4096
#define C_DIM 128
#define SCALE 0.08838834764831845f   // 1/sqrt(128)

// workspace layout (bytes): bf16 hi/lo panels, [b][row][col] 2B elements
#define WS_XHI ((size_t)0)           // X: [b][q][c], scale folded in
#define WS_XLO ((size_t)4 << 20)
#define WS_YHI ((size_t)8 << 20)     // Y: [b][k][c], granule-XOR-swizzled rows
#define WS_YLO ((size_t)12 << 20)
#define WS_NEED ((size_t)16 << 20)

static __device__ __forceinline__ short bf16_rne(float v) {
    unsigned int u = __float_as_uint(v);
    return (short)((u + 0x7fffu + ((u >> 16) & 1u)) >> 16);
}

// ---------------- pre-kernel: transpose [c][k] -> [k][c], fp32 -> bf16 hi+lo ----------------
__global__ __launch_bounds__(256) void conv_kernel(const float* __restrict__ x,
                                                   const float* __restrict__ y,
                                                   char* __restrict__ ws)
{
    __shared__ float tile[64][65];
    int id = blockIdx.x;
    const int isY = (id >= 512);
    id &= 511;
    const int b  = id >> 7;
    const int c0 = ((id >> 6) & 1) * 64;
    const int k0 = (id & 63) * 64;
    const float* src = (isY ? y : x) + ((size_t)b * C_DIM + c0) * NPIX + k0;
    const int t = threadIdx.x;

    // read 64(c) x 64(k), coalesced along k
    {
        const int cl = (t & 15) * 4;
        #pragma unroll
        for (int i = 0; i < 4; ++i) {
            const int r = (t >> 4) + i * 16;
            const float4 v = *(const float4*)(src + (size_t)r * NPIX + cl);
            tile[r][cl]     = v.x;
            tile[r][cl + 1] = v.y;
            tile[r][cl + 2] = v.z;
            tile[r][cl + 3] = v.w;
        }
    }
    __syncthreads();

    char* dhi = ws + (isY ? WS_YHI : WS_XHI) + (size_t)b * (NPIX * C_DIM * 2);
    char* dlo = ws + (isY ? WS_YLO : WS_XLO) + (size_t)b * (NPIX * C_DIM * 2);
    const float sc = isY ? 1.0f : SCALE;

    #pragma unroll
    for (int j = 0; j < 2; ++j) {
        const int gid = t * 2 + j;
        const int k   = gid >> 3;      // local out row (key/query index)
        const int gg  = gid & 7;       // local granule (8 channels = 16B)
        short hi8[8], lo8[8];
        #pragma unroll
        for (int u = 0; u < 8; ++u) {
            const float v = tile[gg * 8 + u][k] * sc;
            const short h = bf16_rne(v);
            const float hv = __uint_as_float(((unsigned int)(unsigned short)h) << 16);
            hi8[u] = h;
            lo8[u] = bf16_rne(v - hv);   // v - hv exact in fp32
        }
        const int kk = k0 + k;
        int G = (c0 >> 3) + gg;          // global granule index 0..15
        if (isY) G ^= (kk & 7);          // bank swizzle for conflict-free MFMA B reads
        const size_t off = (size_t)kk * 256 + (size_t)G * 16;
        *(bf16x8*)(dhi + off) = *(bf16x8*)hi8;
        *(bf16x8*)(dlo + off) = *(bf16x8*)lo8;
    }
}

// ---------------- main kernel: flash attention -> grid expectation, bf16 hi/lo MFMA ----------------
#define TQ 32
#define TK 128

__global__ __launch_bounds__(256, 2) void uv_mfma_kernel(const char* __restrict__ ws,
                                                         float* __restrict__ out)
{
    __shared__ char Ys[TK * 256 * 2];   // hi tile at 0 (32KB), lo tile at +32KB
    __shared__ float red[4][TQ][3];

    const int t    = threadIdx.x;
    const int w    = t >> 6;
    const int l    = t & 63;
    const int n16  = l & 15;
    const int quad = l >> 4;

    const int wg  = blockIdx.x;
    const int xcd = wg & 7;
    const int idx = wg >> 3;                    // 0..63
    const int b   = xcd >> 1;                   // 2 XCDs per batch: Y panel fits 4MB L2
    const int qtile = ((xcd & 1) << 6) | idx;   // 0..127
    const int q0  = qtile * TQ;

    const char* Xhi = ws + WS_XHI + (size_t)b * (NPIX * 256);
    const char* Xlo = ws + WS_XLO + (size_t)b * (NPIX * 256);
    const char* Yhi = ws + WS_YHI + (size_t)b * (NPIX * 256);
    const char* Ylo = ws + WS_YLO + (size_t)b * (NPIX * 256);

    // A-fragments (X, scale folded): held in registers for the whole kernel.
    // A[m=lane&15][k = quad*8 + j]; byte off in row = chunk*64 + quad*16
    bf16x8 ah[2][4], al[2][4];
    #pragma unroll
    for (int qg = 0; qg < 2; ++qg) {
        const size_t rowoff = (size_t)(q0 + qg * 16 + n16) * 256 + (size_t)quad * 16;
        #pragma unroll
        for (int c = 0; c < 4; ++c) {
            ah[qg][c] = *(const bf16x8*)(Xhi + rowoff + c * 64);
            al[qg][c] = *(const bf16x8*)(Xlo + rowoff + c * 64);
        }
    }

    // wave w owns keys [w*32, w*32+32) of each 128-key tile (2 groups of 16)
    int basea[2], xorv[2];
    float gx[2];
    #pragma unroll
    for (int kg = 0; kg < 2; ++kg) {
        const int keyl = w * 32 + kg * 16 + n16;
        basea[kg] = keyl * 256;
        xorv[kg]  = (keyl & 7) * 16;
        gx[kg]    = (float)(keyl & 63) + 0.5f;
    }
    const int   qoff = quad * 16;
    const float gyw  = (float)(w >> 1) + 0.5f;

    float den[8], nu[8], nv[8];
    #pragma unroll
    for (int i = 0; i < 8; ++i) { den[i] = 0.f; nu[i] = 0.f; nv[i] = 0.f; }

    for (int kt = 0; kt < NPIX / TK; ++kt) {
        __syncthreads();   // all waves done reading previous Ys
        {
            const char* ghi = Yhi + (size_t)kt * 32768;
            const char* glo = Ylo + (size_t)kt * 32768;
            #pragma unroll
            for (int i = 0; i < 8; ++i) {
                const int off = i * 4096 + w * 1024;
                __builtin_amdgcn_global_load_lds(
                    (const __attribute__((address_space(1))) void*)(ghi + off + l * 16),
                    (__attribute__((address_space(3))) void*)(&Ys[off]), 16, 0, 0);
            }
            #pragma unroll
            for (int i = 0; i < 8; ++i) {
                const int off = i * 4096 + w * 1024;
                __builtin_amdgcn_global_load_lds(
                    (const __attribute__((address_space(1))) void*)(glo + off + l * 16),
                    (__attribute__((address_space(3))) void*)(&Ys[32768 + off]), 16, 0, 0);
            }
        }
        __syncthreads();   // vmcnt(0) drained by compiler before barrier

        f32x4 acc[2][2];
        #pragma unroll
        for (int qg = 0; qg < 2; ++qg)
            #pragma unroll
            for (int kg = 0; kg < 2; ++kg)
                acc[qg][kg] = (f32x4){0.f, 0.f, 0.f, 0.f};

        #pragma unroll
        for (int c = 0; c < 4; ++c) {
            bf16x8 bh[2], bl[2];
            #pragma unroll
            for (int kg = 0; kg < 2; ++kg) {
                const int addr = basea[kg] + ((c * 64 + qoff) ^ xorv[kg]);
                bh[kg] = *(const bf16x8*)(&Ys[addr]);
                bl[kg] = *(const bf16x8*)(&Ys[32768 + addr]);
            }
            #pragma unroll
            for (int qg = 0; qg < 2; ++qg)
                #pragma unroll
                for (int kg = 0; kg < 2; ++kg) {
                    acc[qg][kg] = __builtin_amdgcn_mfma_f32_16x16x32_bf16(ah[qg][c], bh[kg], acc[qg][kg], 0, 0, 0);
                    acc[qg][kg] = __builtin_amdgcn_mfma_f32_16x16x32_bf16(ah[qg][c], bl[kg], acc[qg][kg], 0, 0, 0);
                    acc[qg][kg] = __builtin_amdgcn_mfma_f32_16x16x32_bf16(al[qg][c], bh[kg], acc[qg][kg], 0, 0, 0);
                }
        }

        // softmax accumulation without max-subtraction: |s| <= ~6.5, exp safe in fp32
        const float gy = 2.0f * (float)kt + gyw;
        #pragma unroll
        for (int qg = 0; qg < 2; ++qg)
            #pragma unroll
            for (int kg = 0; kg < 2; ++kg)
                #pragma unroll
                for (int r = 0; r < 4; ++r) {
                    const float p = __expf(acc[qg][kg][r]);
                    const int row = qg * 4 + r;
                    den[row] += p;
                    nu[row]  += p * gx[kg];
                    nv[row]  += p * gy;
                }
    }

    // reduce across the 16 cols (lanes) of each row
    #pragma unroll
    for (int i = 0; i < 8; ++i) {
        #pragma unroll
        for (int mk = 8; mk >= 1; mk >>= 1) {
            den[i] += __shfl_xor(den[i], mk);
            nu[i]  += __shfl_xor(nu[i],  mk);
            nv[i]  += __shfl_xor(nv[i],  mk);
        }
    }
    if (n16 == 0) {
        #pragma unroll
        for (int qg = 0; qg < 2; ++qg)
            #pragma unroll
            for (int r = 0; r < 4; ++r) {
                const int row = qg * 16 + quad * 4 + r;
                red[w][row][0] = den[qg * 4 + r];
                red[w][row][1] = nu[qg * 4 + r];
                red[w][row][2] = nv[qg * 4 + r];
            }
    }
    __syncthreads();
    if (t < TQ) {
        float d = 0.f, u = 0.f, v = 0.f;
        #pragma unroll
        for (int ww = 0; ww < 4; ++ww) {
            d += red[ww][t][0];
            u += red[ww][t][1];
            v += red[ww][t][2];
        }
        const float inv = 1.0f / d;
        const int q = q0 + t;
        *(float2*)(out + ((size_t)b * NPIX + q) * 2) =
            make_float2(u * inv * 0.03125f - 1.0f, v * inv * 0.03125f - 1.0f);
    }
}

// ---------------- fallback (round-1 fp32 kernel) if workspace too small ----------------
#define NTHREADS 256
__global__ __launch_bounds__(NTHREADS, 2) void uv_attn_kernel(
    const float* __restrict__ x, const float* __restrict__ y, float* __restrict__ out)
{
    __shared__ float Xs[C_DIM][TQ];
    __shared__ float Ysf[64][TK];
    const int tid = threadIdx.x;
    const int wgid = blockIdx.x;
    const int xcd = wgid & 7;
    const int jj_ = wgid >> 3;
    const int b = xcd & 3;
    const int qtile = ((xcd >> 2) << 6) | jj_;
    const int q0 = qtile * TQ;
    const float scale = SCALE;
    const float* xb = x + (size_t)b * C_DIM * NPIX + q0;
    {
        const int cr = tid >> 3;
        const int cc = (tid & 7) << 2;
        #pragma unroll
        for (int i = 0; i < 4; ++i) {
            float4 v = *(const float4*)(xb + (size_t)(cr + (i << 5)) * NPIX + cc);
            v.x *= scale; v.y *= scale; v.z *= scale; v.w *= scale;
            *(float4*)(&Xs[cr + (i << 5)][cc]) = v;
        }
    }
    const int rg = tid >> 4;
    const int lane16 = tid & 15;
    const int r0 = rg << 1;
    const int col0 = lane16 << 3;
    float gxv[8];
    #pragma unroll
    for (int j2 = 0; j2 < 8; ++j2) gxv[j2] = (float)((col0 & 63) + j2) + 0.5f;
    const float gyb = (float)(lane16 >> 3) + 0.5f;
    float m_run[2] = {-INFINITY, -INFINITY};
    float den[2] = {0.f, 0.f}, nu[2] = {0.f, 0.f}, nv[2] = {0.f, 0.f};
    const int yr = tid >> 5;
    const int yc = (tid & 31) << 2;
    const float* ybase = y + (size_t)b * C_DIM * NPIX;
    for (int kt = 0; kt < NPIX / TK; ++kt) {
        float S[2][8];
        #pragma unroll
        for (int r = 0; r < 2; ++r)
            #pragma unroll
            for (int j2 = 0; j2 < 8; ++j2) S[r][j2] = 0.f;
        #pragma unroll
        for (int cb = 0; cb < 2; ++cb) {
            __syncthreads();
            const float* yt = ybase + (size_t)(cb << 6) * NPIX + kt * TK;
            #pragma unroll
            for (int i = 0; i < 8; ++i)
                *(float4*)(&Ysf[yr + (i << 3)][yc]) =
                    *(const float4*)(yt + (size_t)(yr + (i << 3)) * NPIX + yc);
            __syncthreads();
            const int cbase = cb << 6;
            #pragma unroll 16
            for (int c = 0; c < 64; ++c) {
                const float2 xa = *(const float2*)(&Xs[cbase + c][r0]);
                const float4 ya = *(const float4*)(&Ysf[c][col0]);
                const float4 yb4 = *(const float4*)(&Ysf[c][col0 + 4]);
                S[0][0] += xa.x * ya.x;  S[0][1] += xa.x * ya.y;
                S[0][2] += xa.x * ya.z;  S[0][3] += xa.x * ya.w;
                S[0][4] += xa.x * yb4.x; S[0][5] += xa.x * yb4.y;
                S[0][6] += xa.x * yb4.z; S[0][7] += xa.x * yb4.w;
                S[1][0] += xa.y * ya.x;  S[1][1] += xa.y * ya.y;
                S[1][2] += xa.y * ya.z;  S[1][3] += xa.y * ya.w;
                S[1][4] += xa.y * yb4.x; S[1][5] += xa.y * yb4.y;
                S[1][6] += xa.y * yb4.z; S[1][7] += xa.y * yb4.w;
            }
        }
        const float gy = gyb + 2.0f * (float)kt;
        #pragma unroll
        for (int r = 0; r < 2; ++r) {
            float tmax = S[r][0];
            #pragma unroll
            for (int j2 = 1; j2 < 8; ++j2) tmax = fmaxf(tmax, S[r][j2]);
            #pragma unroll
            for (int mk = 8; mk >= 1; mk >>= 1) tmax = fmaxf(tmax, __shfl_xor(tmax, mk, 16));
            const float mnew = fmaxf(m_run[r], tmax);
            const float alpha = __expf(m_run[r] - mnew);
            m_run[r] = mnew;
            float psum = 0.f, pu = 0.f;
            #pragma unroll
            for (int j2 = 0; j2 < 8; ++j2) {
                const float p = __expf(S[r][j2] - mnew);
                psum += p; pu += p * gxv[j2];
            }
            den[r] = den[r] * alpha + psum;
            nu[r] = nu[r] * alpha + pu;
            nv[r] = nv[r] * alpha + gy * psum;
        }
    }
    #pragma unroll
    for (int r = 0; r < 2; ++r)
        #pragma unroll
        for (int mk = 8; mk >= 1; mk >>= 1) {
            den[r] += __shfl_xor(den[r], mk, 16);
            nu[r] += __shfl_xor(nu[r], mk, 16);
            nv[r] += __shfl_xor(nv[r], mk, 16);
        }
    if (lane16 == 0) {
        #pragma unroll
        for (int r = 0; r < 2; ++r) {
            const float inv = 1.0f / den[r];
            const int q = q0 + r0 + r;
            *(float2*)(out + ((size_t)b * NPIX + q) * 2) =
                make_float2(nu[r] * inv * 0.03125f - 1.0f, nv[r] * inv * 0.03125f - 1.0f);
        }
    }
}

extern "C" void kernel_launch(void* const* d_in, const int* in_sizes, int n_in,
                              void* d_out, int out_size, void* d_ws, size_t ws_size,
                              hipStream_t stream) {
    const float* x = (const float*)d_in[0];
    const float* y = (const float*)d_in[1];
    float* out = (float*)d_out;
    if (ws_size >= WS_NEED) {
        hipLaunchKernelGGL(conv_kernel, dim3(1024), dim3(256), 0, stream, x, y, (char*)d_ws);
        hipLaunchKernelGGL(uv_mfma_kernel, dim3(512), dim3(256), 0, stream,
                           (const char*)d_ws, out);
    } else {
        hipLaunchKernelGGL(uv_attn_kernel, dim3(512), dim3(NTHREADS), 0, stream, x, y, out);
    }
}